// Round 3
// baseline (312.837 us; speedup 1.0000x reference)
//
#include <hip/hip_runtime.h>
#include <stdint.h>

#define K_CODES   8192
#define N_PIX     16384
#define D_DIM     64
#define EM_STRIDE 8193   // original embed row stride (K+1)
#define KSUB      8      // 128-code subtiles per block (k-persistence)
#define KGRP      8      // k-groups = 8192 / (KSUB*128)
#define OUT_QUANT 0
#define OUT_DMIN  1048576
#define OUT_IND   (1048576 + 16384)

// async global->LDS, 16B per lane, wave-uniform LDS base + lane*16 dest
__device__ __forceinline__ void gld_lds16(const float* g, float* l) {
    __builtin_amdgcn_global_load_lds(
        (const __attribute__((address_space(1))) uint32_t*)g,
        (__attribute__((address_space(3))) uint32_t*)l, 16, 0, 0);
}

// ---------------------------------------------------------------------------
// Kernel 1: per-code squared norms (stale -> +huge, never selected) and a
// stride-8192 copy of embed so tile staging can use aligned 16B loads.
// ---------------------------------------------------------------------------
__global__ __launch_bounds__(256)
void vq_prep(const float* __restrict__ embed,
             const int* __restrict__ cnt,
             float* __restrict__ ec,     // [64][8192]
             float* __restrict__ cn) {   // [8192]
    int k = blockIdx.x * 256 + threadIdx.x;
    float s = 0.f;
#pragma unroll
    for (int d = 0; d < D_DIM; ++d) {
        float v = embed[d * EM_STRIDE + k];
        ec[d * K_CODES + k] = v;
        s = fmaf(v, v, s);
    }
    cn[k] = (cnt[k] < 1) ? 1.0e30f : s;
}

// ---------------------------------------------------------------------------
// Kernel 2: fp32 distance GEMM + fused running argmin.
// Block = 256 thr, tile 128 rows x 128 codes, k-persistent over 1024 codes.
// e tile (only) in LDS, d-chunked 32 rows -> 16 KB -> 4 blocks/CU, 16 waves.
// x is read per d-step directly from global (16-lane broadcast, L1/L2-hot),
// keeping the LDS pipe at 2 ds_read_b128 per 64 FMAs (FMA-bound, ratio .75).
// ---------------------------------------------------------------------------
__global__ __launch_bounds__(256, 4)
void vq_dist_tile(const float* __restrict__ x,     // [64][16384]
                  const float* __restrict__ ec,    // [64][8192]
                  const float* __restrict__ cn,    // [8192] masked norms
                  float* __restrict__ pmin,        // [KGRP][16384]
                  int*   __restrict__ pidx) {      // [KGRP][16384]
    __shared__ float es[32][128];

    const int nb  = blockIdx.x & 127;   // 128 row blocks
    const int kg  = blockIdx.x >> 7;    // 8 k-groups of 1024 codes
    const int n0  = nb * 128;
    const int kgb = kg * (KSUB * 128);
    const int t   = threadIdx.x;
    const int lane = t & 63;
    const int w    = t >> 6;            // wave 0..3

    const int g  = t >> 4;              // 0..15 row group
    const int jj = t & 15;              // 0..15 code lane
    const int g4 = g * 4;
    const int j4 = jj * 4;

    // staging lane decomposition (per global_load_lds instr: 2 es rows)
    const int colf = (lane & 31) * 4;   // float col 0..124
    const int rsel = lane >> 5;         // 0/1: which of the 2 rows

    const float* xp  = x + n0 + g4;     // rows g4..g4+3 (+64 for upper half)
    const float* esp = &es[0][j4];

    float acc[8][8];
    float bd[8];
    int   bix[8];
#pragma unroll
    for (int r = 0; r < 8; ++r) {
        bd[r] = 3.0e38f; bix[r] = 0;
#pragma unroll
        for (int c = 0; c < 8; ++c) acc[r][c] = 0.f;
    }

    for (int st = 0; st < KSUB; ++st) {
        const int k0 = kgb + st * 128;

        for (int ch = 0; ch < 2; ++ch) {
            const int d0 = ch * 32;
            __syncthreads();            // previous e-chunk fully consumed
            // ---- stage e chunk [32][128] via async global->LDS ----
#pragma unroll
            for (int i = 0; i < 4; ++i) {
                int q  = w * 4 + i;                 // 0..15 (1KB each)
                int dd = d0 + q * 2 + rsel;
                gld_lds16(ec + dd * K_CODES + k0 + colf, &es[0][0] + q * 256);
            }
            __syncthreads();            // vmcnt(0) drain + barrier
            // ---- compute: 32 d-steps, 64 FMA each; x from global ----
            const float* xpc = xp + d0 * N_PIX;
#pragma unroll 8
            for (int d = 0; d < 32; ++d) {
                float4 xa = *(const float4*)(xpc + d * N_PIX);
                float4 xb = *(const float4*)(xpc + d * N_PIX + 64);
                float4 ea = *(const float4*)(esp + d * 128);
                float4 eb = *(const float4*)(esp + d * 128 + 64);
                acc[0][0] = fmaf(xa.x, ea.x, acc[0][0]);
                acc[0][1] = fmaf(xa.x, ea.y, acc[0][1]);
                acc[0][2] = fmaf(xa.x, ea.z, acc[0][2]);
                acc[0][3] = fmaf(xa.x, ea.w, acc[0][3]);
                acc[0][4] = fmaf(xa.x, eb.x, acc[0][4]);
                acc[0][5] = fmaf(xa.x, eb.y, acc[0][5]);
                acc[0][6] = fmaf(xa.x, eb.z, acc[0][6]);
                acc[0][7] = fmaf(xa.x, eb.w, acc[0][7]);
                acc[1][0] = fmaf(xa.y, ea.x, acc[1][0]);
                acc[1][1] = fmaf(xa.y, ea.y, acc[1][1]);
                acc[1][2] = fmaf(xa.y, ea.z, acc[1][2]);
                acc[1][3] = fmaf(xa.y, ea.w, acc[1][3]);
                acc[1][4] = fmaf(xa.y, eb.x, acc[1][4]);
                acc[1][5] = fmaf(xa.y, eb.y, acc[1][5]);
                acc[1][6] = fmaf(xa.y, eb.z, acc[1][6]);
                acc[1][7] = fmaf(xa.y, eb.w, acc[1][7]);
                acc[2][0] = fmaf(xa.z, ea.x, acc[2][0]);
                acc[2][1] = fmaf(xa.z, ea.y, acc[2][1]);
                acc[2][2] = fmaf(xa.z, ea.z, acc[2][2]);
                acc[2][3] = fmaf(xa.z, ea.w, acc[2][3]);
                acc[2][4] = fmaf(xa.z, eb.x, acc[2][4]);
                acc[2][5] = fmaf(xa.z, eb.y, acc[2][5]);
                acc[2][6] = fmaf(xa.z, eb.z, acc[2][6]);
                acc[2][7] = fmaf(xa.z, eb.w, acc[2][7]);
                acc[3][0] = fmaf(xa.w, ea.x, acc[3][0]);
                acc[3][1] = fmaf(xa.w, ea.y, acc[3][1]);
                acc[3][2] = fmaf(xa.w, ea.z, acc[3][2]);
                acc[3][3] = fmaf(xa.w, ea.w, acc[3][3]);
                acc[3][4] = fmaf(xa.w, eb.x, acc[3][4]);
                acc[3][5] = fmaf(xa.w, eb.y, acc[3][5]);
                acc[3][6] = fmaf(xa.w, eb.z, acc[3][6]);
                acc[3][7] = fmaf(xa.w, eb.w, acc[3][7]);
                acc[4][0] = fmaf(xb.x, ea.x, acc[4][0]);
                acc[4][1] = fmaf(xb.x, ea.y, acc[4][1]);
                acc[4][2] = fmaf(xb.x, ea.z, acc[4][2]);
                acc[4][3] = fmaf(xb.x, ea.w, acc[4][3]);
                acc[4][4] = fmaf(xb.x, eb.x, acc[4][4]);
                acc[4][5] = fmaf(xb.x, eb.y, acc[4][5]);
                acc[4][6] = fmaf(xb.x, eb.z, acc[4][6]);
                acc[4][7] = fmaf(xb.x, eb.w, acc[4][7]);
                acc[5][0] = fmaf(xb.y, ea.x, acc[5][0]);
                acc[5][1] = fmaf(xb.y, ea.y, acc[5][1]);
                acc[5][2] = fmaf(xb.y, ea.z, acc[5][2]);
                acc[5][3] = fmaf(xb.y, ea.w, acc[5][3]);
                acc[5][4] = fmaf(xb.y, eb.x, acc[5][4]);
                acc[5][5] = fmaf(xb.y, eb.y, acc[5][5]);
                acc[5][6] = fmaf(xb.y, eb.z, acc[5][6]);
                acc[5][7] = fmaf(xb.y, eb.w, acc[5][7]);
                acc[6][0] = fmaf(xb.z, ea.x, acc[6][0]);
                acc[6][1] = fmaf(xb.z, ea.y, acc[6][1]);
                acc[6][2] = fmaf(xb.z, ea.z, acc[6][2]);
                acc[6][3] = fmaf(xb.z, ea.w, acc[6][3]);
                acc[6][4] = fmaf(xb.z, eb.x, acc[6][4]);
                acc[6][5] = fmaf(xb.z, eb.y, acc[6][5]);
                acc[6][6] = fmaf(xb.z, eb.z, acc[6][6]);
                acc[6][7] = fmaf(xb.z, eb.w, acc[6][7]);
                acc[7][0] = fmaf(xb.w, ea.x, acc[7][0]);
                acc[7][1] = fmaf(xb.w, ea.y, acc[7][1]);
                acc[7][2] = fmaf(xb.w, ea.z, acc[7][2]);
                acc[7][3] = fmaf(xb.w, ea.w, acc[7][3]);
                acc[7][4] = fmaf(xb.w, eb.x, acc[7][4]);
                acc[7][5] = fmaf(xb.w, eb.y, acc[7][5]);
                acc[7][6] = fmaf(xb.w, eb.z, acc[7][6]);
                acc[7][7] = fmaf(xb.w, eb.w, acc[7][7]);
            }
        }

        // ---- per-subtile epilogue: dist = cn - 2*dot, running argmin ----
        float cnv[8];
#pragma unroll
        for (int c = 0; c < 8; ++c)
            cnv[c] = cn[k0 + j4 + ((c < 4) ? c : 60 + c)];
#pragma unroll
        for (int r = 0; r < 8; ++r) {
#pragma unroll
            for (int c = 0; c < 8; ++c) {    // ascending k, strict <
                float dist = fmaf(-2.f, acc[r][c], cnv[c]);
                int   k    = k0 + j4 + ((c < 4) ? c : 60 + c);
                if (dist < bd[r]) { bd[r] = dist; bix[r] = k; }
                acc[r][c] = 0.f;
            }
        }
    }

    // ---- once per block: reduce across the 16 code lanes, write partial ----
#pragma unroll
    for (int r = 0; r < 8; ++r) {
        float d = bd[r];
        int   i = bix[r];
#pragma unroll
        for (int m = 1; m < 16; m <<= 1) {
            float od = __shfl_xor(d, m, 64);
            int   oi = __shfl_xor(i, m, 64);
            if (od < d || (od == d && oi < i)) { d = od; i = oi; }
        }
        if (jj == 0) {
            int lr = (r < 4) ? (g4 + r) : (64 + g4 + r - 4);
            pmin[kg * N_PIX + n0 + lr] = d;
            pidx[kg * N_PIX + n0 + lr] = i;
        }
    }
}

// ---------------------------------------------------------------------------
// Kernel 3: reduce 8 k-group partials per row, add ||x||^2, gather winning
// code column, write all three outputs.
// ---------------------------------------------------------------------------
__global__ __launch_bounds__(256)
void vq_finalize(const float* __restrict__ x,
                 const float* __restrict__ ec,
                 const float* __restrict__ pmin,
                 const int*   __restrict__ pidx,
                 float* __restrict__ out) {
    int n = blockIdx.x * 256 + threadIdx.x;   // 0..16383
    float best = 3.0e38f;
    int   bi   = 0x7fffffff;
#pragma unroll
    for (int kb = 0; kb < KGRP; ++kb) {
        float m = pmin[kb * N_PIX + n];
        int   i = pidx[kb * N_PIX + n];
        if (m < best || (m == best && i < bi)) { best = m; bi = i; }
    }
    float rn = 0.f;
#pragma unroll
    for (int d = 0; d < D_DIM; ++d) {
        float v = x[d * N_PIX + n];
        rn = fmaf(v, v, rn);
    }
    out[OUT_DMIN + n] = best + rn;
    out[OUT_IND  + n] = (float)bi;
#pragma unroll
    for (int d = 0; d < D_DIM; ++d)
        out[OUT_QUANT + d * N_PIX + n] = ec[d * K_CODES + bi];
}

// ---------------------------------------------------------------------------
extern "C" void kernel_launch(void* const* d_in, const int* in_sizes, int n_in,
                              void* d_out, int out_size, void* d_ws, size_t ws_size,
                              hipStream_t stream) {
    const float* x     = (const float*)d_in[0];   // [1,64,128,128]
    const float* embed = (const float*)d_in[1];   // [64,8193]
    const int*   cnt   = (const int*)d_in[2];     // [8192]
    float* out = (float*)d_out;

    // workspace layout
    float* ec   = (float*)d_ws;                                      // 2 MB
    float* cn   = (float*)((char*)d_ws + (size_t)2 * 1024 * 1024);   // 32 KB
    float* pmin = (float*)((char*)d_ws + (size_t)2 * 1024 * 1024 + 32768);
    int*   pidx = (int*)((char*)pmin + (size_t)KGRP * N_PIX * 4);

    vq_prep<<<K_CODES / 256, 256, 0, stream>>>(embed, cnt, ec, cn);
    vq_dist_tile<<<KGRP * 128, 256, 0, stream>>>(x, ec, cn, pmin, pidx);
    vq_finalize<<<N_PIX / 256, 256, 0, stream>>>(x, ec, pmin, pidx, out);
}

// Round 4
// 222.487 us; speedup vs baseline: 1.4061x; 1.4061x over previous
//
#include <hip/hip_runtime.h>
#include <stdint.h>

#define K_CODES   8192
#define N_PIX     16384
#define D_DIM     64
#define EM_STRIDE 8193   // original embed row stride (K+1)
#define KSUB      8      // 256-code subtiles per block (k-persistence)
#define KGRP      4      // 8192 / (KSUB*256)
#define DCH       32     // d-chunk rows staged per barrier pair
#define OUT_QUANT 0
#define OUT_DMIN  1048576
#define OUT_IND   (1048576 + 16384)

// async global->LDS, 16B per lane, wave-uniform LDS base + lane*16 dest
__device__ __forceinline__ void gld_lds16(const float* g, float* l) {
    __builtin_amdgcn_global_load_lds(
        (const __attribute__((address_space(1))) uint32_t*)g,
        (__attribute__((address_space(3))) uint32_t*)l, 16, 0, 0);
}

// ---------------------------------------------------------------------------
// Kernel 1: per-code squared norms (stale -> +huge, never selected) and a
// stride-8192 copy of embed so tile staging can use aligned 16B loads.
// ---------------------------------------------------------------------------
__global__ __launch_bounds__(256)
void vq_prep(const float* __restrict__ embed,
             const int* __restrict__ cnt,
             float* __restrict__ ec,     // [64][8192]
             float* __restrict__ cn) {   // [8192]
    int k = blockIdx.x * 256 + threadIdx.x;
    float s = 0.f;
#pragma unroll
    for (int d = 0; d < D_DIM; ++d) {
        float v = embed[d * EM_STRIDE + k];
        ec[d * K_CODES + k] = v;
        s = fmaf(v, v, s);
    }
    cn[k] = (cnt[k] < 1) ? 1.0e30f : s;
}

// ---------------------------------------------------------------------------
// Kernel 2: fp32 distance GEMM + fused running argmin.
// 256 thr = 4 waves. Wave w owns 8 consecutive rows (x values are wave-
// uniform -> scalar s_load path, zero VGPR/LDS cost). Lane owns 4 codes
// (acc[8][4] = 32 VGPR). e tile in LDS, d-chunked 32 -> 32 KB -> 5 blk/CU.
// Only LDS op in the inner loop: 1 ds_read_b128 per 32 FMA instrs -> the
// LDS pipe (shared by 4 SIMDs) runs at 48/128 cycles: FMA-bound.
// Block covers 32 rows x 2048 codes (8 subtiles), running argmin in regs.
// ---------------------------------------------------------------------------
__global__ __launch_bounds__(256, 4)
void vq_dist_tile(const float* __restrict__ x,     // [64][16384]
                  const float* __restrict__ ec,    // [64][8192]
                  const float* __restrict__ cn,    // [8192] masked norms
                  float* __restrict__ pmin,        // [KGRP][16384]
                  int*   __restrict__ pidx) {      // [KGRP][16384]
    __shared__ float es[DCH][256];

    const int nb  = blockIdx.x & 511;    // 512 row blocks (32 rows each)
    const int kg  = blockIdx.x >> 9;     // 4 k-groups of 2048 codes
    const int n0  = nb * 32;
    const int kgb = kg * (KSUB * 256);
    const int t    = threadIdx.x;
    const int lane = t & 63;
    const int w    = t >> 6;             // wave 0..3
    const int wu   = __builtin_amdgcn_readfirstlane(w);

    // x rows for this wave: n0 + wu*8 .. +7 (uniform across all 64 lanes)
    const float* __restrict__ xw = x + n0 + wu * 8;
    const float* esl = &es[0][0] + lane * 4;

    float acc[8][4];
    float bd[8];
    int   bix[8];
#pragma unroll
    for (int r = 0; r < 8; ++r) {
        bd[r] = 3.0e38f; bix[r] = 0;
#pragma unroll
        for (int c = 0; c < 4; ++c) acc[r][c] = 0.f;
    }

    for (int st = 0; st < KSUB; ++st) {
        const int k0 = kgb + st * 256;

        for (int ch = 0; ch < 2; ++ch) {
            const int d0 = ch * DCH;
            __syncthreads();             // previous e-chunk fully consumed
            // ---- stage e chunk [32][256]: one row per wave-instr ----
#pragma unroll
            for (int i = 0; i < 8; ++i) {
                int dd = d0 + i * 4 + w;
                gld_lds16(ec + dd * K_CODES + k0 + lane * 4,
                          &es[0][0] + (i * 4 + w) * 256);
            }
            __syncthreads();             // vmcnt(0) drain + barrier
            // ---- compute: 32 d-steps, 32 FMA instrs each ----
            const float* xc = xw + d0 * N_PIX;
#pragma unroll 4
            for (int d = 0; d < DCH; ++d) {
                float4 ea = *(const float4*)(esl + d * 256);
                const float* xr = xc + d * N_PIX;
                float x0 = xr[0], x1 = xr[1], x2 = xr[2], x3 = xr[3];
                float x4 = xr[4], x5 = xr[5], x6 = xr[6], x7 = xr[7];
                acc[0][0] = fmaf(x0, ea.x, acc[0][0]);
                acc[0][1] = fmaf(x0, ea.y, acc[0][1]);
                acc[0][2] = fmaf(x0, ea.z, acc[0][2]);
                acc[0][3] = fmaf(x0, ea.w, acc[0][3]);
                acc[1][0] = fmaf(x1, ea.x, acc[1][0]);
                acc[1][1] = fmaf(x1, ea.y, acc[1][1]);
                acc[1][2] = fmaf(x1, ea.z, acc[1][2]);
                acc[1][3] = fmaf(x1, ea.w, acc[1][3]);
                acc[2][0] = fmaf(x2, ea.x, acc[2][0]);
                acc[2][1] = fmaf(x2, ea.y, acc[2][1]);
                acc[2][2] = fmaf(x2, ea.z, acc[2][2]);
                acc[2][3] = fmaf(x2, ea.w, acc[2][3]);
                acc[3][0] = fmaf(x3, ea.x, acc[3][0]);
                acc[3][1] = fmaf(x3, ea.y, acc[3][1]);
                acc[3][2] = fmaf(x3, ea.z, acc[3][2]);
                acc[3][3] = fmaf(x3, ea.w, acc[3][3]);
                acc[4][0] = fmaf(x4, ea.x, acc[4][0]);
                acc[4][1] = fmaf(x4, ea.y, acc[4][1]);
                acc[4][2] = fmaf(x4, ea.z, acc[4][2]);
                acc[4][3] = fmaf(x4, ea.w, acc[4][3]);
                acc[5][0] = fmaf(x5, ea.x, acc[5][0]);
                acc[5][1] = fmaf(x5, ea.y, acc[5][1]);
                acc[5][2] = fmaf(x5, ea.z, acc[5][2]);
                acc[5][3] = fmaf(x5, ea.w, acc[5][3]);
                acc[6][0] = fmaf(x6, ea.x, acc[6][0]);
                acc[6][1] = fmaf(x6, ea.y, acc[6][1]);
                acc[6][2] = fmaf(x6, ea.z, acc[6][2]);
                acc[6][3] = fmaf(x6, ea.w, acc[6][3]);
                acc[7][0] = fmaf(x7, ea.x, acc[7][0]);
                acc[7][1] = fmaf(x7, ea.y, acc[7][1]);
                acc[7][2] = fmaf(x7, ea.z, acc[7][2]);
                acc[7][3] = fmaf(x7, ea.w, acc[7][3]);
            }
        }

        // ---- per-subtile epilogue: dist = cn - 2*dot, running argmin ----
        const int kb = k0 + lane * 4;                 // lane's 4 codes
        float4 cn4 = *(const float4*)(cn + kb);
        float cnv[4] = {cn4.x, cn4.y, cn4.z, cn4.w};
#pragma unroll
        for (int r = 0; r < 8; ++r) {
#pragma unroll
            for (int c = 0; c < 4; ++c) {             // ascending k: strict <
                float dist = fmaf(-2.f, acc[r][c], cnv[c]);
                if (dist < bd[r]) { bd[r] = dist; bix[r] = kb + c; }
                acc[r][c] = 0.f;
            }
        }
    }

    // ---- once per block: butterfly-min across the 64 lanes, write ----
#pragma unroll
    for (int r = 0; r < 8; ++r) {
        float d = bd[r];
        int   i = bix[r];
#pragma unroll
        for (int m = 1; m < 64; m <<= 1) {
            float od = __shfl_xor(d, m, 64);
            int   oi = __shfl_xor(i, m, 64);
            if (od < d || (od == d && oi < i)) { d = od; i = oi; }
        }
        if (lane == 0) {
            pmin[kg * N_PIX + n0 + wu * 8 + r] = d;
            pidx[kg * N_PIX + n0 + wu * 8 + r] = i;
        }
    }
}

// ---------------------------------------------------------------------------
// Kernel 3: reduce 4 k-group partials per row, add ||x||^2, gather winning
// code column, write all three outputs.
// ---------------------------------------------------------------------------
__global__ __launch_bounds__(256)
void vq_finalize(const float* __restrict__ x,
                 const float* __restrict__ ec,
                 const float* __restrict__ pmin,
                 const int*   __restrict__ pidx,
                 float* __restrict__ out) {
    int n = blockIdx.x * 256 + threadIdx.x;   // 0..16383
    float best = 3.0e38f;
    int   bi   = 0x7fffffff;
#pragma unroll
    for (int kb = 0; kb < KGRP; ++kb) {
        float m = pmin[kb * N_PIX + n];
        int   i = pidx[kb * N_PIX + n];
        if (m < best || (m == best && i < bi)) { best = m; bi = i; }
    }
    float rn = 0.f;
#pragma unroll
    for (int d = 0; d < D_DIM; ++d) {
        float v = x[d * N_PIX + n];
        rn = fmaf(v, v, rn);
    }
    out[OUT_DMIN + n] = best + rn;
    out[OUT_IND  + n] = (float)bi;
#pragma unroll
    for (int d = 0; d < D_DIM; ++d)
        out[OUT_QUANT + d * N_PIX + n] = ec[d * K_CODES + bi];
}

// ---------------------------------------------------------------------------
extern "C" void kernel_launch(void* const* d_in, const int* in_sizes, int n_in,
                              void* d_out, int out_size, void* d_ws, size_t ws_size,
                              hipStream_t stream) {
    const float* x     = (const float*)d_in[0];   // [1,64,128,128]
    const float* embed = (const float*)d_in[1];   // [64,8193]
    const int*   cnt   = (const int*)d_in[2];     // [8192]
    float* out = (float*)d_out;

    // workspace layout
    float* ec   = (float*)d_ws;                                      // 2 MB
    float* cn   = (float*)((char*)d_ws + (size_t)2 * 1024 * 1024);   // 32 KB
    float* pmin = (float*)((char*)d_ws + (size_t)2 * 1024 * 1024 + 32768);
    int*   pidx = (int*)((char*)pmin + (size_t)KGRP * N_PIX * 4);

    vq_prep<<<K_CODES / 256, 256, 0, stream>>>(embed, cnt, ec, cn);
    vq_dist_tile<<<KGRP * 512, 256, 0, stream>>>(x, ec, cn, pmin, pidx);
    vq_finalize<<<N_PIX / 256, 256, 0, stream>>>(x, ec, pmin, pidx, out);
}